// Round 2
// baseline (340.025 us; speedup 1.0000x reference)
//
#include <hip/hip_runtime.h>
#include <hip/hip_bf16.h>
#include <math.h>

typedef __bf16 bf16x8 __attribute__((ext_vector_type(8)));
typedef __bf16 bf16x4 __attribute__((ext_vector_type(4)));
typedef __bf16 bf16x2 __attribute__((ext_vector_type(2)));
typedef float f32x4 __attribute__((ext_vector_type(4)));

#define B_SZ 32
#define T_SZ 2048
#define D_SZ 512
#define K_SZ 128
#define TC 32
#define NC 64   // T_SZ / TC

__device__ __forceinline__ float softplus_f(float x){
  return x > 20.f ? x : log1pf(expf(x));
}

// ---------------------------------------------------------------------------
// Kernel 1: spectral norm power iteration + W_sn -> bf16 (pre-scaled by 1/sigma)
// ---------------------------------------------------------------------------
__global__ __launch_bounds__(512) void sn_prep(const float* __restrict__ W,
                                               const float* __restrict__ u_sn,
                                               __bf16* __restrict__ Wb){
  __shared__ float red[512];
  __shared__ float vsh[512];
  __shared__ float ush[128];
  const int t = threadIdx.x;
  if (t < 128) ush[t] = u_sn[t];
  __syncthreads();
  // t1[d] = sum_k W[k,d] * u[k]   (coalesced over d)
  float t1 = 0.f;
  #pragma unroll 8
  for (int k = 0; k < K_SZ; ++k) t1 += W[k*D_SZ + t] * ush[k];
  red[t] = t1 * t1;
  __syncthreads();
  for (int s = 256; s > 0; s >>= 1){ if (t < s) red[t] += red[t+s]; __syncthreads(); }
  const float n1 = sqrtf(red[0]);
  vsh[t] = t1 / (n1 + 1e-6f);
  __syncthreads();
  // t2[k] = sum_d W[k,d] * v[d]  (float4 per row)
  float t2 = 0.f;
  if (t < 128){
    const float4* Wr = (const float4*)(W + (size_t)t * D_SZ);
    const float4* vp = (const float4*)vsh;
    #pragma unroll 8
    for (int d = 0; d < D_SZ/4; ++d){
      const float4 a = Wr[d], v = vp[d];
      t2 += a.x*v.x + a.y*v.y + a.z*v.z + a.w*v.w;
    }
  }
  __syncthreads();
  red[t] = (t < 128) ? t2*t2 : 0.f;
  __syncthreads();
  for (int s = 256; s > 0; s >>= 1){ if (t < s) red[t] += red[t+s]; __syncthreads(); }
  const float n2sq = red[0];
  const float sigma = n2sq / (sqrtf(n2sq) + 1e-6f);   // u1 . (W v)
  const float inv = 1.f / sigma;
  for (int i = t; i < K_SZ*D_SZ/4; i += 512){
    const float4 v = ((const float4*)W)[i];
    bf16x4 o; o[0]=(__bf16)(v.x*inv); o[1]=(__bf16)(v.y*inv);
    o[2]=(__bf16)(v.z*inv); o[3]=(__bf16)(v.w*inv);
    ((bf16x4*)Wb)[i] = o;
  }
}

// ---------------------------------------------------------------------------
// Kernel 2: u = x @ W_sn^T   (M=65536, N=128, K=512), bf16 MFMA, bf16 out
// Staging: each thread loads 32B contiguous (8 threads cover a 64-col row),
// converts fp32->bf16, writes one fragment chunk to LDS.
// ---------------------------------------------------------------------------
__global__ __launch_bounds__(256) void gemm_xw(const float* __restrict__ X,
                                               const __bf16* __restrict__ Wb,
                                               __bf16* __restrict__ U){
  __shared__ bf16x8 As[1024];   // 16 fragment blocks of 16x32 (bf16), 16 KB
  __shared__ bf16x8 Bs[1024];
  const int tid = threadIdx.x;
  const int lane = tid & 63;
  const int wid = tid >> 6;
  const int wm = wid >> 1, wn = wid & 1;
  const int rowbase = blockIdx.x * 128;
  const int L15 = lane & 15, Lq = lane >> 4;
  f32x4 acc[4][4] = {};

  for (int kk = 0; kk < D_SZ; kk += 64){
    #pragma unroll
    for (int r = 0; r < 4; ++r){
      const int fc = tid + 256*r;           // 0..1023 chunk id
      const int row = fc >> 3, cg = fc & 7; // row 0..127, col-group-of-8
      const float4* p = (const float4*)(X + (size_t)(rowbase + row)*D_SZ + kk + cg*8);
      const float4 v0 = p[0], v1 = p[1];
      bf16x8 f;
      f[0]=(__bf16)v0.x; f[1]=(__bf16)v0.y; f[2]=(__bf16)v0.z; f[3]=(__bf16)v0.w;
      f[4]=(__bf16)v1.x; f[5]=(__bf16)v1.y; f[6]=(__bf16)v1.z; f[7]=(__bf16)v1.w;
      const int fb = ((row >> 4) << 1) | (cg >> 2);       // fragment block
      const int ll = (row & 15) | ((cg & 3) << 4);        // lane within frag
      As[fb*64 + ll] = f;
      Bs[fb*64 + ll] = *(const bf16x8*)(Wb + (size_t)row*D_SZ + kk + cg*8);
    }
    __syncthreads();
    #pragma unroll
    for (int s = 0; s < 2; ++s){
      bf16x8 af[4], bfr[4];
      #pragma unroll
      for (int ii = 0; ii < 4; ++ii) af[ii]  = As[((wm*4+ii)*2 + s)*64 + lane];
      #pragma unroll
      for (int jj = 0; jj < 4; ++jj) bfr[jj] = Bs[((wn*4+jj)*2 + s)*64 + lane];
      #pragma unroll
      for (int ii = 0; ii < 4; ++ii)
        #pragma unroll
        for (int jj = 0; jj < 4; ++jj)
          acc[ii][jj] = __builtin_amdgcn_mfma_f32_16x16x32_bf16(af[ii], bfr[jj], acc[ii][jj], 0, 0, 0);
    }
    __syncthreads();
  }
  // epilogue: C/D layout col = lane&15, row = (lane>>4)*4 + reg (m89-verified)
  #pragma unroll
  for (int ii = 0; ii < 4; ++ii){
    const int m = rowbase + (wm*4+ii)*16 + (Lq << 2);
    #pragma unroll
    for (int jj = 0; jj < 4; ++jj){
      const int n = (wn*4+jj)*16 + L15;
      #pragma unroll
      for (int r = 0; r < 4; ++r)
        U[(size_t)(m + r)*K_SZ + n] = (__bf16)acc[ii][jj][r];
    }
  }
}

// ---------------------------------------------------------------------------
// Kernel 3 (pass A): per-chunk summaries. Thread = (chunk, 2 k-channels).
// Block = 256 threads = 4 chunks x 64 k-pairs. Grid = (NC/4, B).
// ---------------------------------------------------------------------------
__global__ __launch_bounds__(256) void pass_a(
    const float* __restrict__ alpha_mod, const float* __restrict__ omega_mod,
    const __bf16* __restrict__ Uarr, const float* __restrict__ dt,
    const float* __restrict__ tau_mod, const float* __restrict__ s_real,
    const float* __restrict__ s_imag, const float* __restrict__ tau_raw,
    const float* __restrict__ bvec,
    float2* __restrict__ sumA, float2* __restrict__ sumT,
    float2* __restrict__ Zr, float2* __restrict__ Zi){
  const int t = threadIdx.x;
  const int kh = t & 63;        // k-pair index: k = kh*2, kh*2+1
  const int cl = t >> 6;        // chunk-local 0..3
  const int b = blockIdx.y;
  const int c = blockIdx.x*4 + cl;
  const int t0 = c * TC;
  __shared__ float sdt[4*TC], ssc[4*TC];
  if (t < 128){
    const int tg = blockIdx.x*4*TC + t;
    sdt[t] = dt[b*T_SZ + tg];
    ssc[t] = __expf(tau_mod[b*T_SZ + tg]);
  }
  __syncthreads();
  const float tau = softplus_f(tau_raw[0]) + 1e-3f;
  const float2 sr = ((const float2*)s_real)[kh];
  const float2 si = ((const float2*)s_imag)[kh];
  const float2 bk = ((const float2*)bvec)[kh];
  const float a0[2] = {(softplus_f(sr.x)+1e-6f)*tau, (softplus_f(sr.y)+1e-6f)*tau};
  const float w0[2] = {si.x*tau, si.y*tau};
  float zr[2]={0,0}, zs[2]={0,0}, sA[2]={0,0}, sT[2]={0,0};
  const float* sd = sdt + cl*TC;
  const float* ss = ssc + cl*TC;
  const size_t row = (size_t)(b*T_SZ + t0);
  const float2* amp = (const float2*)(alpha_mod + row*K_SZ) + kh;
  const float2* omp = (const float2*)(omega_mod + row*K_SZ) + kh;
  const bf16x2* up  = (const bf16x2*)(Uarr + row*K_SZ) + kh;
  #pragma unroll 4
  for (int i = 0; i < TC; ++i){
    const float2 am = amp[(size_t)i*64];
    const float2 om = omp[(size_t)i*64];
    const bf16x2 u2 = up[(size_t)i*64];
    const float scdt = ss[i] * sd[i];
    #pragma unroll
    for (int j = 0; j < 2; ++j){
      const float ad = a0[j] * __expf(j ? am.y : am.x) * scdt;
      const float th = w0[j] * __expf(j ? om.y : om.x) * scdt;
      const float rho = __expf(-ad);
      float st, ct; __sincosf(th, &st, &ct);
      const float uu = (float)u2[j] + (j ? bk.y : bk.x);
      const float nr = rho*(zr[j]*ct - zs[j]*st) + uu;
      const float ns = rho*(zr[j]*st + zs[j]*ct);
      zr[j] = nr; zs[j] = ns;
      sA[j] += ad; sT[j] += th;
    }
  }
  const size_t idx = ((size_t)(b*NC + c))*64 + kh;
  sumA[idx] = make_float2(sA[0], sA[1]);
  sumT[idx] = make_float2(sT[0], sT[1]);
  Zr[idx]   = make_float2(zr[0], zr[1]);
  Zi[idx]   = make_float2(zs[0], zs[1]);
}

// ---------------------------------------------------------------------------
// Kernel 4 (pass B): scan chunk summaries. Thread = (b, 2 k-channels).
// ---------------------------------------------------------------------------
__global__ __launch_bounds__(256) void pass_b(
    const float2* __restrict__ sumA, const float2* __restrict__ sumT,
    const float2* __restrict__ Zr, const float2* __restrict__ Zi,
    float2* __restrict__ Cr, float2* __restrict__ Ci){
  const int id = blockIdx.x*256 + threadIdx.x;  // 0..2047 = b*64 + kh
  const int b = id >> 6, kh = id & 63;
  float er[2]={0,0}, ei[2]={0,0};
  #pragma unroll 4
  for (int c = 0; c < NC; ++c){
    const size_t idx = ((size_t)(b*NC + c))*64 + kh;
    Cr[idx] = make_float2(er[0], er[1]);
    Ci[idx] = make_float2(ei[0], ei[1]);
    const float2 sa = sumA[idx], st4 = sumT[idx];
    const float2 zr = Zr[idx],   zi  = Zi[idx];
    #pragma unroll
    for (int j = 0; j < 2; ++j){
      const float rho = __expf(-(j ? sa.y : sa.x));
      float st, ct; __sincosf(j ? st4.y : st4.x, &st, &ct);
      const float ar = rho*ct, ai = rho*st;
      const float zrj = j ? zr.y : zr.x, zij = j ? zi.y : zi.x;
      const float nr = zrj + ar*er[j] - ai*ei[j];
      const float ni = zij + ar*ei[j] + ai*er[j];
      er[j] = nr; ei[j] = ni;
    }
  }
}

// ---------------------------------------------------------------------------
// Kernel 5 (pass C): replay chunks from carry-in, write [B,T,2K] output
// ---------------------------------------------------------------------------
__global__ __launch_bounds__(256) void pass_c(
    const float* __restrict__ alpha_mod, const float* __restrict__ omega_mod,
    const __bf16* __restrict__ Uarr, const float* __restrict__ dt,
    const float* __restrict__ tau_mod, const float* __restrict__ s_real,
    const float* __restrict__ s_imag, const float* __restrict__ tau_raw,
    const float* __restrict__ bvec,
    const float2* __restrict__ Cr, const float2* __restrict__ Ci,
    float* __restrict__ out){
  const int t = threadIdx.x;
  const int kh = t & 63;
  const int cl = t >> 6;
  const int b = blockIdx.y;
  const int c = blockIdx.x*4 + cl;
  const int t0 = c * TC;
  __shared__ float sdt[4*TC], ssc[4*TC];
  if (t < 128){
    const int tg = blockIdx.x*4*TC + t;
    sdt[t] = dt[b*T_SZ + tg];
    ssc[t] = __expf(tau_mod[b*T_SZ + tg]);
  }
  __syncthreads();
  const float tau = softplus_f(tau_raw[0]) + 1e-3f;
  const float2 sr = ((const float2*)s_real)[kh];
  const float2 si = ((const float2*)s_imag)[kh];
  const float2 bk = ((const float2*)bvec)[kh];
  const float a0[2] = {(softplus_f(sr.x)+1e-6f)*tau, (softplus_f(sr.y)+1e-6f)*tau};
  const float w0[2] = {si.x*tau, si.y*tau};
  const size_t cidx = ((size_t)(b*NC + c))*64 + kh;
  const float2 cr = Cr[cidx], cim = Ci[cidx];
  float zr[2] = {cr.x, cr.y}, zs[2] = {cim.x, cim.y};
  const float* sd = sdt + cl*TC;
  const float* ss = ssc + cl*TC;
  const size_t row = (size_t)(b*T_SZ + t0);
  const float2* amp = (const float2*)(alpha_mod + row*K_SZ) + kh;
  const float2* omp = (const float2*)(omega_mod + row*K_SZ) + kh;
  const bf16x2* up  = (const bf16x2*)(Uarr + row*K_SZ) + kh;
  float2* outC = (float2*)(out + row*(2*K_SZ)) + kh;          // stride 128 float2 per t
  float2* outS = outC + 64;
  #pragma unroll 4
  for (int i = 0; i < TC; ++i){
    const float2 am = amp[(size_t)i*64];
    const float2 om = omp[(size_t)i*64];
    const bf16x2 u2 = up[(size_t)i*64];
    const float scdt = ss[i] * sd[i];
    #pragma unroll
    for (int j = 0; j < 2; ++j){
      const float ad = a0[j] * __expf(j ? am.y : am.x) * scdt;
      const float th = w0[j] * __expf(j ? om.y : om.x) * scdt;
      const float rho = __expf(-ad);
      float st, ct; __sincosf(th, &st, &ct);
      const float uu = (float)u2[j] + (j ? bk.y : bk.x);
      const float nr = rho*(zr[j]*ct - zs[j]*st) + uu;
      const float ns = rho*(zr[j]*st + zs[j]*ct);
      zr[j] = nr; zs[j] = ns;
    }
    outC[(size_t)i*128] = make_float2(zr[0], zr[1]);
    outS[(size_t)i*128] = make_float2(zs[0], zs[1]);
  }
}

// ---------------------------------------------------------------------------
extern "C" void kernel_launch(void* const* d_in, const int* in_sizes, int n_in,
                              void* d_out, int out_size, void* d_ws, size_t ws_size,
                              hipStream_t stream){
  (void)in_sizes; (void)n_in; (void)out_size; (void)ws_size;
  const float* x         = (const float*)d_in[0];
  const float* dt        = (const float*)d_in[1];
  const float* alpha_mod = (const float*)d_in[2];
  const float* omega_mod = (const float*)d_in[3];
  const float* tau_mod   = (const float*)d_in[4];
  const float* s_real    = (const float*)d_in[5];
  const float* s_imag    = (const float*)d_in[6];
  const float* tau_raw   = (const float*)d_in[7];
  const float* W         = (const float*)d_in[8];
  const float* bvec      = (const float*)d_in[9];
  const float* u_sn      = (const float*)d_in[10];
  float* out = (float*)d_out;

  char* w = (char*)d_ws;
  __bf16* Wb = (__bf16*)w;                                  // 128 KiB
  __bf16* U  = (__bf16*)(w + 131072);                       // 16 MiB (bf16 u)
  size_t off = 131072 + (size_t)B_SZ*T_SZ*K_SZ*2;
  const size_t SUMN = (size_t)B_SZ*NC*K_SZ*4;               // 1 MiB each
  float2* sumA = (float2*)(w + off); off += SUMN;
  float2* sumT = (float2*)(w + off); off += SUMN;
  float2* Zr   = (float2*)(w + off); off += SUMN;
  float2* Zi   = (float2*)(w + off); off += SUMN;
  float2* Cr   = (float2*)(w + off); off += SUMN;
  float2* Ci   = (float2*)(w + off); off += SUMN;

  sn_prep<<<1, 512, 0, stream>>>(W, u_sn, Wb);
  gemm_xw<<<(B_SZ*T_SZ)/128, 256, 0, stream>>>(x, Wb, U);
  pass_a<<<dim3(NC/4, B_SZ), 256, 0, stream>>>(alpha_mod, omega_mod, U, dt, tau_mod,
                                               s_real, s_imag, tau_raw, bvec,
                                               sumA, sumT, Zr, Zi);
  pass_b<<<8, 256, 0, stream>>>(sumA, sumT, Zr, Zi, Cr, Ci);
  pass_c<<<dim3(NC/4, B_SZ), 256, 0, stream>>>(alpha_mod, omega_mod, U, dt, tau_mod,
                                               s_real, s_imag, tau_raw, bvec,
                                               Cr, Ci, out);
}

// Round 3
// 335.307 us; speedup vs baseline: 1.0141x; 1.0141x over previous
//
#include <hip/hip_runtime.h>
#include <hip/hip_bf16.h>
#include <math.h>

typedef __bf16 bf16x8 __attribute__((ext_vector_type(8)));
typedef __bf16 bf16x4 __attribute__((ext_vector_type(4)));
typedef __bf16 bf16x2 __attribute__((ext_vector_type(2)));
typedef float f32x4 __attribute__((ext_vector_type(4)));

#define B_SZ 32
#define T_SZ 2048
#define D_SZ 512
#define K_SZ 128
#define TC 32
#define NC 64   // T_SZ / TC

__device__ __forceinline__ float softplus_f(float x){
  return x > 20.f ? x : log1pf(expf(x));
}

// ---------------------------------------------------------------------------
// Kernel 1: spectral norm power iteration + W_sn -> bf16 (pre-scaled by 1/sigma)
// ---------------------------------------------------------------------------
__global__ __launch_bounds__(512) void sn_prep(const float* __restrict__ W,
                                               const float* __restrict__ u_sn,
                                               __bf16* __restrict__ Wb){
  __shared__ float red[512];
  __shared__ float vsh[512];
  __shared__ float ush[128];
  const int t = threadIdx.x;
  if (t < 128) ush[t] = u_sn[t];
  __syncthreads();
  // t1[d] = sum_k W[k,d] * u[k]   (coalesced over d)
  float t1 = 0.f;
  #pragma unroll 8
  for (int k = 0; k < K_SZ; ++k) t1 += W[k*D_SZ + t] * ush[k];
  red[t] = t1 * t1;
  __syncthreads();
  for (int s = 256; s > 0; s >>= 1){ if (t < s) red[t] += red[t+s]; __syncthreads(); }
  const float n1 = sqrtf(red[0]);
  vsh[t] = t1 / (n1 + 1e-6f);
  __syncthreads();
  // t2[k] = sum_d W[k,d] * v[d]  (float4 per row)
  float t2 = 0.f;
  if (t < 128){
    const float4* Wr = (const float4*)(W + (size_t)t * D_SZ);
    const float4* vp = (const float4*)vsh;
    #pragma unroll 8
    for (int d = 0; d < D_SZ/4; ++d){
      const float4 a = Wr[d], v = vp[d];
      t2 += a.x*v.x + a.y*v.y + a.z*v.z + a.w*v.w;
    }
  }
  __syncthreads();
  red[t] = (t < 128) ? t2*t2 : 0.f;
  __syncthreads();
  for (int s = 256; s > 0; s >>= 1){ if (t < s) red[t] += red[t+s]; __syncthreads(); }
  const float n2sq = red[0];
  const float sigma = n2sq / (sqrtf(n2sq) + 1e-6f);   // u1 . (W v)
  const float inv = 1.f / sigma;
  for (int i = t; i < K_SZ*D_SZ/4; i += 512){
    const float4 v = ((const float4*)W)[i];
    bf16x4 o; o[0]=(__bf16)(v.x*inv); o[1]=(__bf16)(v.y*inv);
    o[2]=(__bf16)(v.z*inv); o[3]=(__bf16)(v.w*inv);
    ((bf16x4*)Wb)[i] = o;
  }
}

// ---------------------------------------------------------------------------
// Kernel 2: u = x @ W_sn^T   (M=65536, N=128, K=512), bf16 MFMA, bf16 out.
// Double-buffered LDS, one barrier per K-iter, register prefetch of the next
// tile issued right after the barrier so loads complete under MFMA.
// LDS chunks XOR-swizzled: phys = (fb*64+ll) ^ cg -> conflict-free writes
// ((row&7)^cg spans all 8 bank groups) AND conflict-free reads.
// ---------------------------------------------------------------------------
__global__ __launch_bounds__(256) void gemm_xw(const float* __restrict__ X,
                                               const __bf16* __restrict__ Wb,
                                               __bf16* __restrict__ U){
  __shared__ bf16x8 As[2][1024];   // 32 KB
  __shared__ bf16x8 Bs[2][1024];   // 32 KB
  const int tid = threadIdx.x;
  const int lane = tid & 63;
  const int wid = tid >> 6;
  const int wm = wid >> 1, wn = wid & 1;
  const int rowbase = blockIdx.x * 128;
  const int L15 = lane & 15, Lq = lane >> 4;
  f32x4 acc[4][4] = {};

  // staging coordinates: thread covers rows rowA+32r, col group cg (8 cols)
  const int rowA = tid >> 3;      // 0..31
  const int cg   = tid & 7;
  const int colo = cg * 8;
  int pidx[4];
  #pragma unroll
  for (int r = 0; r < 4; ++r){
    const int row = rowA + 32*r;
    const int fb = ((row >> 4) << 1) | (cg >> 2);
    const int ll = (row & 15) | ((cg & 3) << 4);
    pidx[r] = (fb*64 + ll) ^ cg;
  }
  const float* Xb  = X  + (size_t)(rowbase + rowA)*D_SZ + colo;
  const __bf16* Bb = Wb + (size_t)rowA*D_SZ + colo;

  float4 va[4], vb[4];
  bf16x8 wreg[4];
  #pragma unroll
  for (int r = 0; r < 4; ++r){
    const float4* q = (const float4*)(Xb + (size_t)(32*r)*D_SZ);
    va[r] = q[0]; vb[r] = q[1];
    wreg[r] = *(const bf16x8*)(Bb + (size_t)(32*r)*D_SZ);
  }

  int pb = 0;
  for (int kk = 0; kk < D_SZ; kk += 64){
    #pragma unroll
    for (int r = 0; r < 4; ++r){
      bf16x8 f;
      f[0]=(__bf16)va[r].x; f[1]=(__bf16)va[r].y; f[2]=(__bf16)va[r].z; f[3]=(__bf16)va[r].w;
      f[4]=(__bf16)vb[r].x; f[5]=(__bf16)vb[r].y; f[6]=(__bf16)vb[r].z; f[7]=(__bf16)vb[r].w;
      As[pb][pidx[r]] = f;
      Bs[pb][pidx[r]] = wreg[r];
    }
    __syncthreads();
    if (kk + 64 < D_SZ){
      #pragma unroll
      for (int r = 0; r < 4; ++r){
        const float4* q = (const float4*)(Xb + (size_t)(32*r)*D_SZ + kk + 64);
        va[r] = q[0]; vb[r] = q[1];
        wreg[r] = *(const bf16x8*)(Bb + (size_t)(32*r)*D_SZ + kk + 64);
      }
    }
    #pragma unroll
    for (int s = 0; s < 2; ++s){
      bf16x8 af[4], bfr[4];
      const int swz = (s << 2) | (lane >> 4);
      #pragma unroll
      for (int ii = 0; ii < 4; ++ii){
        const int fb = ((wm*4+ii) << 1) | s;
        af[ii] = As[pb][(fb*64 + lane) ^ swz];
      }
      #pragma unroll
      for (int jj = 0; jj < 4; ++jj){
        const int fb = ((wn*4+jj) << 1) | s;
        bfr[jj] = Bs[pb][(fb*64 + lane) ^ swz];
      }
      #pragma unroll
      for (int ii = 0; ii < 4; ++ii)
        #pragma unroll
        for (int jj = 0; jj < 4; ++jj)
          acc[ii][jj] = __builtin_amdgcn_mfma_f32_16x16x32_bf16(af[ii], bfr[jj], acc[ii][jj], 0, 0, 0);
    }
    pb ^= 1;
  }
  // epilogue: C/D layout col = lane&15, row = (lane>>4)*4 + reg (m89-verified)
  #pragma unroll
  for (int ii = 0; ii < 4; ++ii){
    const int m = rowbase + (wm*4+ii)*16 + (Lq << 2);
    #pragma unroll
    for (int jj = 0; jj < 4; ++jj){
      const int n = (wn*4+jj)*16 + L15;
      #pragma unroll
      for (int r = 0; r < 4; ++r)
        U[(size_t)(m + r)*K_SZ + n] = (__bf16)acc[ii][jj][r];
    }
  }
}

// ---------------------------------------------------------------------------
// Kernel 3 (pass A): per-chunk summaries. Thread = (chunk, 2 k-channels).
// Block = 256 threads = 4 chunks x 64 k-pairs. Grid = (NC/4, B).
// ---------------------------------------------------------------------------
__global__ __launch_bounds__(256) void pass_a(
    const float* __restrict__ alpha_mod, const float* __restrict__ omega_mod,
    const __bf16* __restrict__ Uarr, const float* __restrict__ dt,
    const float* __restrict__ tau_mod, const float* __restrict__ s_real,
    const float* __restrict__ s_imag, const float* __restrict__ tau_raw,
    const float* __restrict__ bvec,
    float2* __restrict__ sumA, float2* __restrict__ sumT,
    float2* __restrict__ Zr, float2* __restrict__ Zi){
  const int t = threadIdx.x;
  const int kh = t & 63;        // k-pair index: k = kh*2, kh*2+1
  const int cl = t >> 6;        // chunk-local 0..3
  const int b = blockIdx.y;
  const int c = blockIdx.x*4 + cl;
  const int t0 = c * TC;
  __shared__ float sdt[4*TC], ssc[4*TC];
  if (t < 128){
    const int tg = blockIdx.x*4*TC + t;
    sdt[t] = dt[b*T_SZ + tg];
    ssc[t] = __expf(tau_mod[b*T_SZ + tg]);
  }
  __syncthreads();
  const float tau = softplus_f(tau_raw[0]) + 1e-3f;
  const float2 sr = ((const float2*)s_real)[kh];
  const float2 si = ((const float2*)s_imag)[kh];
  const float2 bk = ((const float2*)bvec)[kh];
  const float a0[2] = {(softplus_f(sr.x)+1e-6f)*tau, (softplus_f(sr.y)+1e-6f)*tau};
  const float w0[2] = {si.x*tau, si.y*tau};
  float zr[2]={0,0}, zs[2]={0,0}, sA[2]={0,0}, sT[2]={0,0};
  const float* sd = sdt + cl*TC;
  const float* ss = ssc + cl*TC;
  const size_t row = (size_t)(b*T_SZ + t0);
  const float2* amp = (const float2*)(alpha_mod + row*K_SZ) + kh;
  const float2* omp = (const float2*)(omega_mod + row*K_SZ) + kh;
  const bf16x2* up  = (const bf16x2*)(Uarr + row*K_SZ) + kh;
  #pragma unroll 4
  for (int i = 0; i < TC; ++i){
    const float2 am = amp[(size_t)i*64];
    const float2 om = omp[(size_t)i*64];
    const bf16x2 u2 = up[(size_t)i*64];
    const float scdt = ss[i] * sd[i];
    #pragma unroll
    for (int j = 0; j < 2; ++j){
      const float ad = a0[j] * __expf(j ? am.y : am.x) * scdt;
      const float th = w0[j] * __expf(j ? om.y : om.x) * scdt;
      const float rho = __expf(-ad);
      float st, ct; __sincosf(th, &st, &ct);
      const float uu = (float)u2[j] + (j ? bk.y : bk.x);
      const float nr = rho*(zr[j]*ct - zs[j]*st) + uu;
      const float ns = rho*(zr[j]*st + zs[j]*ct);
      zr[j] = nr; zs[j] = ns;
      sA[j] += ad; sT[j] += th;
    }
  }
  const size_t idx = ((size_t)(b*NC + c))*64 + kh;
  sumA[idx] = make_float2(sA[0], sA[1]);
  sumT[idx] = make_float2(sT[0], sT[1]);
  Zr[idx]   = make_float2(zr[0], zr[1]);
  Zi[idx]   = make_float2(zs[0], zs[1]);
}

// ---------------------------------------------------------------------------
// Kernel 4 (pass B): scan chunk summaries. Thread = (b, 2 k-channels).
// ---------------------------------------------------------------------------
__global__ __launch_bounds__(256) void pass_b(
    const float2* __restrict__ sumA, const float2* __restrict__ sumT,
    const float2* __restrict__ Zr, const float2* __restrict__ Zi,
    float2* __restrict__ Cr, float2* __restrict__ Ci){
  const int id = blockIdx.x*256 + threadIdx.x;  // 0..2047 = b*64 + kh
  const int b = id >> 6, kh = id & 63;
  float er[2]={0,0}, ei[2]={0,0};
  #pragma unroll 4
  for (int c = 0; c < NC; ++c){
    const size_t idx = ((size_t)(b*NC + c))*64 + kh;
    Cr[idx] = make_float2(er[0], er[1]);
    Ci[idx] = make_float2(ei[0], ei[1]);
    const float2 sa = sumA[idx], st4 = sumT[idx];
    const float2 zr = Zr[idx],   zi  = Zi[idx];
    #pragma unroll
    for (int j = 0; j < 2; ++j){
      const float rho = __expf(-(j ? sa.y : sa.x));
      float st, ct; __sincosf(j ? st4.y : st4.x, &st, &ct);
      const float ar = rho*ct, ai = rho*st;
      const float zrj = j ? zr.y : zr.x, zij = j ? zi.y : zi.x;
      const float nr = zrj + ar*er[j] - ai*ei[j];
      const float ni = zij + ar*ei[j] + ai*er[j];
      er[j] = nr; ei[j] = ni;
    }
  }
}

// ---------------------------------------------------------------------------
// Kernel 5 (pass C): replay chunks from carry-in, write [B,T,2K] output
// ---------------------------------------------------------------------------
__global__ __launch_bounds__(256) void pass_c(
    const float* __restrict__ alpha_mod, const float* __restrict__ omega_mod,
    const __bf16* __restrict__ Uarr, const float* __restrict__ dt,
    const float* __restrict__ tau_mod, const float* __restrict__ s_real,
    const float* __restrict__ s_imag, const float* __restrict__ tau_raw,
    const float* __restrict__ bvec,
    const float2* __restrict__ Cr, const float2* __restrict__ Ci,
    float* __restrict__ out){
  const int t = threadIdx.x;
  const int kh = t & 63;
  const int cl = t >> 6;
  const int b = blockIdx.y;
  const int c = blockIdx.x*4 + cl;
  const int t0 = c * TC;
  __shared__ float sdt[4*TC], ssc[4*TC];
  if (t < 128){
    const int tg = blockIdx.x*4*TC + t;
    sdt[t] = dt[b*T_SZ + tg];
    ssc[t] = __expf(tau_mod[b*T_SZ + tg]);
  }
  __syncthreads();
  const float tau = softplus_f(tau_raw[0]) + 1e-3f;
  const float2 sr = ((const float2*)s_real)[kh];
  const float2 si = ((const float2*)s_imag)[kh];
  const float2 bk = ((const float2*)bvec)[kh];
  const float a0[2] = {(softplus_f(sr.x)+1e-6f)*tau, (softplus_f(sr.y)+1e-6f)*tau};
  const float w0[2] = {si.x*tau, si.y*tau};
  const size_t cidx = ((size_t)(b*NC + c))*64 + kh;
  const float2 cr = Cr[cidx], cim = Ci[cidx];
  float zr[2] = {cr.x, cr.y}, zs[2] = {cim.x, cim.y};
  const float* sd = sdt + cl*TC;
  const float* ss = ssc + cl*TC;
  const size_t row = (size_t)(b*T_SZ + t0);
  const float2* amp = (const float2*)(alpha_mod + row*K_SZ) + kh;
  const float2* omp = (const float2*)(omega_mod + row*K_SZ) + kh;
  const bf16x2* up  = (const bf16x2*)(Uarr + row*K_SZ) + kh;
  float2* outC = (float2*)(out + row*(2*K_SZ)) + kh;          // stride 128 float2 per t
  float2* outS = outC + 64;
  #pragma unroll 4
  for (int i = 0; i < TC; ++i){
    const float2 am = amp[(size_t)i*64];
    const float2 om = omp[(size_t)i*64];
    const bf16x2 u2 = up[(size_t)i*64];
    const float scdt = ss[i] * sd[i];
    #pragma unroll
    for (int j = 0; j < 2; ++j){
      const float ad = a0[j] * __expf(j ? am.y : am.x) * scdt;
      const float th = w0[j] * __expf(j ? om.y : om.x) * scdt;
      const float rho = __expf(-ad);
      float st, ct; __sincosf(th, &st, &ct);
      const float uu = (float)u2[j] + (j ? bk.y : bk.x);
      const float nr = rho*(zr[j]*ct - zs[j]*st) + uu;
      const float ns = rho*(zr[j]*st + zs[j]*ct);
      zr[j] = nr; zs[j] = ns;
    }
    outC[(size_t)i*128] = make_float2(zr[0], zr[1]);
    outS[(size_t)i*128] = make_float2(zs[0], zs[1]);
  }
}

// ---------------------------------------------------------------------------
extern "C" void kernel_launch(void* const* d_in, const int* in_sizes, int n_in,
                              void* d_out, int out_size, void* d_ws, size_t ws_size,
                              hipStream_t stream){
  (void)in_sizes; (void)n_in; (void)out_size; (void)ws_size;
  const float* x         = (const float*)d_in[0];
  const float* dt        = (const float*)d_in[1];
  const float* alpha_mod = (const float*)d_in[2];
  const float* omega_mod = (const float*)d_in[3];
  const float* tau_mod   = (const float*)d_in[4];
  const float* s_real    = (const float*)d_in[5];
  const float* s_imag    = (const float*)d_in[6];
  const float* tau_raw   = (const float*)d_in[7];
  const float* W         = (const float*)d_in[8];
  const float* bvec      = (const float*)d_in[9];
  const float* u_sn      = (const float*)d_in[10];
  float* out = (float*)d_out;

  char* w = (char*)d_ws;
  __bf16* Wb = (__bf16*)w;                                  // 128 KiB
  __bf16* U  = (__bf16*)(w + 131072);                       // 16 MiB (bf16 u)
  size_t off = 131072 + (size_t)B_SZ*T_SZ*K_SZ*2;
  const size_t SUMN = (size_t)B_SZ*NC*K_SZ*4;               // 1 MiB each
  float2* sumA = (float2*)(w + off); off += SUMN;
  float2* sumT = (float2*)(w + off); off += SUMN;
  float2* Zr   = (float2*)(w + off); off += SUMN;
  float2* Zi   = (float2*)(w + off); off += SUMN;
  float2* Cr   = (float2*)(w + off); off += SUMN;
  float2* Ci   = (float2*)(w + off); off += SUMN;

  sn_prep<<<1, 512, 0, stream>>>(W, u_sn, Wb);
  gemm_xw<<<(B_SZ*T_SZ)/128, 256, 0, stream>>>(x, Wb, U);
  pass_a<<<dim3(NC/4, B_SZ), 256, 0, stream>>>(alpha_mod, omega_mod, U, dt, tau_mod,
                                               s_real, s_imag, tau_raw, bvec,
                                               sumA, sumT, Zr, Zi);
  pass_b<<<8, 256, 0, stream>>>(sumA, sumT, Zr, Zi, Cr, Ci);
  pass_c<<<dim3(NC/4, B_SZ), 256, 0, stream>>>(alpha_mod, omega_mod, U, dt, tau_mod,
                                               s_real, s_imag, tau_raw, bvec,
                                               Cr, Ci, out);
}